// Round 1
// baseline (92.246 us; speedup 1.0000x reference)
//
#include <hip/hip_runtime.h>
#include <hip/hip_bf16.h>

typedef unsigned short u16;
typedef __attribute__((ext_vector_type(8))) short short8;    // 8 bf16 (4 VGPR) MFMA A/B frag
typedef __attribute__((ext_vector_type(4))) float f32x4;     // MFMA C/D frag
typedef __attribute__((ext_vector_type(8))) unsigned short u16x8;

#define MDIM 4096
#define NDIM 1024
#define KDIM 2048
#define BM 128
#define BN 64
#define BK 64
// gate order in workspace / accumulators
#define G_I 0
#define G_F 1
#define G_C 2
#define G_O 3

// fp32 -> bf16 round-to-nearest-even (inputs are normal floats, no NaN)
static __device__ __forceinline__ u16 f2b(float f) {
    unsigned u = __builtin_bit_cast(unsigned, f);
    unsigned r = u + 0x7fffu + ((u >> 16) & 1u);
    return (u16)(r >> 16);
}

static __device__ __forceinline__ float sigm(float x) {
    return 1.0f / (1.0f + __expf(-x));
}

// async global->LDS 16B copy. LDS dest must be wave-uniform; HW adds lane*16.
static __device__ __forceinline__ void gload16(const void* g, void* l) {
    __builtin_amdgcn_global_load_lds(
        (__attribute__((address_space(1))) void*)g,
        (__attribute__((address_space(3))) void*)l, 16, 0, 0);
}

// ---------------------------------------------------------------------------
// Pack x,h -> bf16 xh workspace, tiled [mblk][kblk][128][64] with XOR slot
// swizzle pre-applied: element (row,k) at row*64 + (((k>>3)^row)&7)*8 + (k&7)
// ---------------------------------------------------------------------------
__global__ void conv_xh_kernel(const float* __restrict__ x,
                               const float* __restrict__ h,
                               u16* __restrict__ xh_ws) {
    const int kblk = blockIdx.x;  // 0..31
    const int mblk = blockIdx.y;  // 0..31
    u16* dst = xh_ws + (size_t)(mblk * 32 + kblk) * (BM * BK);
    const float* src0;
    int kofs;
    if (kblk < 16) { src0 = x; kofs = kblk * 64; }
    else           { src0 = h; kofs = kblk * 64 - 1024; }
    for (int i = threadIdx.x; i < BM * 8; i += 256) {
        int mr = i >> 3, s = i & 7;
        const float* p = src0 + (size_t)(mblk * BM + mr) * 1024 + kofs + s * 8;
        float4 a = reinterpret_cast<const float4*>(p)[0];
        float4 b = reinterpret_cast<const float4*>(p)[1];
        u16x8 o;
        o[0] = f2b(a.x); o[1] = f2b(a.y); o[2] = f2b(a.z); o[3] = f2b(a.w);
        o[4] = f2b(b.x); o[5] = f2b(b.y); o[6] = f2b(b.z); o[7] = f2b(b.w);
        *reinterpret_cast<u16x8*>(dst + mr * 64 + ((s ^ (mr & 7)) << 3)) = o;
    }
}

// ---------------------------------------------------------------------------
// Transpose-convert W_g [K][N] fp32 -> bf16 [g][nblk][kblk][64 n][64 k],
// same XOR slot swizzle on the k axis within each 64-row.
// ---------------------------------------------------------------------------
__global__ void conv_w_kernel(const float* __restrict__ Wi,
                              const float* __restrict__ Wf,
                              const float* __restrict__ Wc,
                              const float* __restrict__ Wo,
                              u16* __restrict__ w_ws) {
    const int kblk = blockIdx.x;  // 0..31
    const int nblk = blockIdx.y;  // 0..15
    const int g    = blockIdx.z;  // 0..3
    const float* W = (g == 0) ? Wi : (g == 1) ? Wf : (g == 2) ? Wc : Wo;
    u16* dst = w_ws + (size_t)((g * 16 + nblk) * 32 + kblk) * (BN * BK);
    const int nr = threadIdx.x & 63;
    const int s0 = threadIdx.x >> 6;   // 0..3
    const int n  = nblk * 64 + nr;
    for (int s = s0; s < 8; s += 4) {
        const float* p = W + (size_t)(kblk * 64 + s * 8) * 1024 + n;
        u16x8 o;
#pragma unroll
        for (int j = 0; j < 8; ++j) o[j] = f2b(p[(size_t)j * 1024]);
        *reinterpret_cast<u16x8*>(dst + nr * 64 + ((s ^ (nr & 7)) << 3)) = o;
    }
}

// ---------------------------------------------------------------------------
// Fused 4-gate GEMM + LSTM pointwise epilogue.
// Block: 512 threads (8 waves, 4M x 2N). Tile: 128(M) x 64(N) x 4 gates.
// Per wave per gate: 32x32 sub-tile. BK=64, mfma_f32_16x16x32_bf16.
// ---------------------------------------------------------------------------
__global__ __launch_bounds__(512) void lstm_gemm_kernel(
    const u16* __restrict__ xh_ws, const u16* __restrict__ w_ws,
    const float* __restrict__ c_in,
    const float* __restrict__ b_i, const float* __restrict__ b_f,
    const float* __restrict__ b_c, const float* __restrict__ b_o,
    float* __restrict__ h_out, float* __restrict__ c_out) {
    __shared__ u16 lds[BM * BK + 4 * BN * BK];  // 8192 + 16384 elems = 48 KiB
    u16* Al = lds;            // [128][64] swizzled
    u16* Bl = lds + BM * BK;  // 4 x [64][64] swizzled

    const int nblk = blockIdx.x;   // 0..15
    const int mblk = blockIdx.y;   // 0..31
    const int t    = threadIdx.x;
    const int lane = t & 63;
    const int w    = t >> 6;       // 0..7
    const int wm   = w >> 1;       // 0..3
    const int wn   = w & 1;        // 0..1
    const int l15  = lane & 15;
    const int l4   = lane >> 4;

    f32x4 acc[4][2][2] = {};       // [gate][mfrag][nfrag]

    for (int kt = 0; kt < KDIM / BK; ++kt) {
        // ---- stage A tile: 16 KiB, 2 x 16B per thread, linear copy ----
        const u16* Asrc = xh_ws + (size_t)(mblk * 32 + kt) * (BM * BK);
#pragma unroll
        for (int r = 0; r < 2; ++r)
            gload16(Asrc + r * 4096 + w * 512 + lane * 8,
                    Al + r * 4096 + w * 512);
        // ---- stage 4 B tiles: 4 x 8 KiB, 16B per thread each ----
#pragma unroll
        for (int g = 0; g < 4; ++g) {
            const u16* Bsrc = w_ws + (size_t)((g * 16 + nblk) * 32 + kt) * (BN * BK);
            gload16(Bsrc + w * 512 + lane * 8, Bl + g * 4096 + w * 512);
        }
        __syncthreads();   // drains vmcnt -> LDS tile complete

        // ---- compute: 2 k-steps of 32 ----
#pragma unroll
        for (int ks = 0; ks < 2; ++ks) {
            const int kk = ks * 32 + l4 * 8;
            short8 af[2];
#pragma unroll
            for (int mf = 0; mf < 2; ++mf) {
                int row = wm * 32 + mf * 16 + l15;
                af[mf] = *reinterpret_cast<const short8*>(
                    Al + row * 64 + ((((kk >> 3) ^ row) & 7) << 3));
            }
#pragma unroll
            for (int g = 0; g < 4; ++g) {
#pragma unroll
                for (int nf = 0; nf < 2; ++nf) {
                    int n = wn * 32 + nf * 16 + l15;
                    short8 bfr = *reinterpret_cast<const short8*>(
                        Bl + g * 4096 + n * 64 + ((((kk >> 3) ^ n) & 7) << 3));
                    acc[g][0][nf] = __builtin_amdgcn_mfma_f32_16x16x32_bf16(
                        af[0], bfr, acc[g][0][nf], 0, 0, 0);
                    acc[g][1][nf] = __builtin_amdgcn_mfma_f32_16x16x32_bf16(
                        af[1], bfr, acc[g][1][nf], 0, 0, 0);
                }
            }
        }
        __syncthreads();   // compute done before next stage overwrites LDS
    }

    // ---- fused LSTM epilogue ----
    const int mBase = mblk * BM + wm * 32;
    const int nBase = nblk * BN + wn * 32;
#pragma unroll
    for (int mf = 0; mf < 2; ++mf) {
#pragma unroll
        for (int nf = 0; nf < 2; ++nf) {
            int n = nBase + nf * 16 + l15;
            float vbi = b_i[n], vbf = b_f[n], vbc = b_c[n], vbo = b_o[n];
#pragma unroll
            for (int r = 0; r < 4; ++r) {
                int m = mBase + mf * 16 + l4 * 4 + r;
                size_t idx = (size_t)m * NDIM + n;
                float gi = sigm(acc[G_I][mf][nf][r] + vbi);
                float gf = sigm(acc[G_F][mf][nf][r] + vbf);
                float gc = tanhf(acc[G_C][mf][nf][r] + vbc);
                float go = sigm(acc[G_O][mf][nf][r] + vbo);
                float ct = gf * c_in[idx] + gi * gc;
                h_out[idx] = go * tanhf(ct);
                c_out[idx] = ct;
            }
        }
    }
}

extern "C" void kernel_launch(void* const* d_in, const int* in_sizes, int n_in,
                              void* d_out, int out_size, void* d_ws, size_t ws_size,
                              hipStream_t stream) {
    const float* x   = (const float*)d_in[0];
    const float* h   = (const float*)d_in[1];
    const float* c   = (const float*)d_in[2];
    const float* Wi  = (const float*)d_in[3];
    const float* Wf  = (const float*)d_in[4];
    const float* Wc  = (const float*)d_in[5];
    const float* Wo  = (const float*)d_in[6];
    const float* bi  = (const float*)d_in[7];
    const float* bf_ = (const float*)d_in[8];
    const float* bc  = (const float*)d_in[9];
    const float* bo  = (const float*)d_in[10];

    float* hout = (float*)d_out;
    float* cout = hout + (size_t)MDIM * NDIM;

    // workspace: bf16 xh [4096][2048] tiled+swizzled, bf16 W^T [4][1024][2048]
    u16* xh_ws = (u16*)d_ws;                       // 16.78 MB
    u16* w_ws  = xh_ws + (size_t)MDIM * KDIM;      // 16.78 MB  (total 33.6 MB)

    conv_xh_kernel<<<dim3(32, 32), 256, 0, stream>>>(x, h, xh_ws);
    conv_w_kernel<<<dim3(32, 16, 4), 256, 0, stream>>>(Wi, Wf, Wc, Wo, w_ws);
    lstm_gemm_kernel<<<dim3(16, 32), 512, 0, stream>>>(
        xh_ws, w_ws, c, bi, bf_, bc, bo, hout, cout);
}

// Round 2
// 92.061 us; speedup vs baseline: 1.0020x; 1.0020x over previous
//
#include <hip/hip_runtime.h>
#include <hip/hip_bf16.h>

typedef unsigned short u16;
typedef __attribute__((ext_vector_type(8))) short short8;    // 8 bf16 (4 VGPR) MFMA A/B frag
typedef __attribute__((ext_vector_type(4))) float f32x4;     // MFMA C/D frag
typedef __attribute__((ext_vector_type(8))) unsigned short u16x8;

#define MDIM 4096
#define NDIM 1024
#define KDIM 2048
#define BM 256       // rows per block
#define BNS 64       // spatial cols per block (x4 gates)
#define BK 64
#define NT (KDIM / BK)   // 32 K-tiles

#define G_I 0
#define G_F 1
#define G_C 2
#define G_O 3

// fp32 -> bf16 round-to-nearest-even
static __device__ __forceinline__ u16 f2b(float f) {
    unsigned u = __builtin_bit_cast(unsigned, f);
    unsigned r = u + 0x7fffu + ((u >> 16) & 1u);
    return (u16)(r >> 16);
}

static __device__ __forceinline__ float sigm(float x) {
    return 1.0f / (1.0f + __expf(-x));
}

// async global->LDS 16B copy. LDS dest wave-uniform; HW adds lane*16.
static __device__ __forceinline__ void gload16(const void* g, void* l) {
    __builtin_amdgcn_global_load_lds(
        (__attribute__((address_space(1))) void*)g,
        (__attribute__((address_space(3))) void*)l, 16, 0, 0);
}

// ---------------------------------------------------------------------------
// Pack x,h -> bf16 xh workspace, tiled [mblk 16][kt 32][256][64] with XOR slot
// swizzle pre-applied: element (row,k) at row*64 + (((k>>3)^row)&7)*8 + (k&7)
// ---------------------------------------------------------------------------
__global__ void conv_xh_kernel(const float* __restrict__ x,
                               const float* __restrict__ h,
                               u16* __restrict__ xh_ws) {
    const int kblk = blockIdx.x;  // 0..31
    const int mblk = blockIdx.y;  // 0..15
    u16* dst = xh_ws + (size_t)(mblk * 32 + kblk) * (BM * BK);
    const float* src0;
    int kofs;
    if (kblk < 16) { src0 = x; kofs = kblk * 64; }
    else           { src0 = h; kofs = kblk * 64 - 1024; }
    for (int i = threadIdx.x; i < BM * 8; i += 256) {
        int mr = i >> 3, s = i & 7;
        const float* p = src0 + (size_t)(mblk * BM + mr) * 1024 + kofs + s * 8;
        float4 a = reinterpret_cast<const float4*>(p)[0];
        float4 b = reinterpret_cast<const float4*>(p)[1];
        u16x8 o;
        o[0] = f2b(a.x); o[1] = f2b(a.y); o[2] = f2b(a.z); o[3] = f2b(a.w);
        o[4] = f2b(b.x); o[5] = f2b(b.y); o[6] = f2b(b.z); o[7] = f2b(b.w);
        *reinterpret_cast<u16x8*>(dst + mr * 64 + ((s ^ (mr & 7)) << 3)) = o;
    }
}

// ---------------------------------------------------------------------------
// Transpose-convert W_g [K][N] fp32 -> bf16 [g][nblk 16][kt 32][64 n][64 k],
// same XOR slot swizzle on the k axis within each 64-row.
// ---------------------------------------------------------------------------
__global__ void conv_w_kernel(const float* __restrict__ Wi,
                              const float* __restrict__ Wf,
                              const float* __restrict__ Wc,
                              const float* __restrict__ Wo,
                              u16* __restrict__ w_ws) {
    const int kblk = blockIdx.x;  // 0..31
    const int nblk = blockIdx.y;  // 0..15
    const int g    = blockIdx.z;  // 0..3
    const float* W = (g == 0) ? Wi : (g == 1) ? Wf : (g == 2) ? Wc : Wo;
    u16* dst = w_ws + (size_t)((g * 16 + nblk) * 32 + kblk) * (BNS * BK);
    const int nr = threadIdx.x & 63;
    const int s0 = threadIdx.x >> 6;   // 0..3
    const int n  = nblk * 64 + nr;
    for (int s = s0; s < 8; s += 4) {
        const float* p = W + (size_t)(kblk * 64 + s * 8) * 1024 + n;
        u16x8 o;
#pragma unroll
        for (int j = 0; j < 8; ++j) o[j] = f2b(p[(size_t)j * 1024]);
        *reinterpret_cast<u16x8*>(dst + nr * 64 + ((s ^ (nr & 7)) << 3)) = o;
    }
}

// ---------------------------------------------------------------------------
// Fused 4-gate GEMM + LSTM epilogue, 8-phase-style schedule (T3+T4+T5).
// Block: 512 thr (8 waves = 4 m-quadrants x 2 n-halves). Tile 256m x 64n x 4g.
// Per wave: 64m x 32n x 4g; per K-tile: 4 phases (one gate each), 16 MFMA/phase.
// Staging 1 K-tile ahead, chunk/phase: {A-half0, A-half1, B-g01, B-g23};
// counted vmcnt(4) @phase1-end, vmcnt(2) @phase3-end — never 0 in main loop.
// ---------------------------------------------------------------------------
__global__ __launch_bounds__(512, 2) void lstm_gemm_kernel(
    const u16* __restrict__ xh_ws, const u16* __restrict__ w_ws,
    const float* __restrict__ c_in,
    const float* __restrict__ b_i, const float* __restrict__ b_f,
    const float* __restrict__ b_c, const float* __restrict__ b_o,
    float* __restrict__ h_out, float* __restrict__ c_out) {
    // per buffer: A 256x64 (16384 u16) + B 4x64x64 (16384 u16); x2 dbuf = 128 KiB
    __shared__ u16 lds[2 * 32768];

    const int nblk = blockIdx.x;   // 0..15
    const int mblk = blockIdx.y;   // 0..15
    const int t    = threadIdx.x;
    const int lane = t & 63;
    const int w    = t >> 6;       // 0..7
    const int wq   = w >> 1;       // m-quadrant 0..3 (64 rows each)
    const int wn   = w & 1;        // n-half 0..1 (32 cols each)
    const int l15  = lane & 15;
    const int l4   = lane >> 4;

    const u16* Abase = xh_ws + (size_t)mblk * (NT * BM * BK);      // + kt*16384
    const size_t bstr = (size_t)NT * 4096;                         // per (g,nblk) tile run
    const u16* Bbase = w_ws + (size_t)nblk * bstr;                 // gate g: + g*16*bstr + kt*4096

    // LDS read offsets (u16 elems), swizzle-aware; all statically indexed
    int aoff[4][2];   // [mf][ks]
#pragma unroll
    for (int mf = 0; mf < 4; ++mf) {
        int row = wq * 64 + mf * 16 + l15;
#pragma unroll
        for (int ks = 0; ks < 2; ++ks) {
            int kc = ks * 4 + l4;
            aoff[mf][ks] = row * 64 + (((kc ^ row) & 7) << 3);
        }
    }
    int boff[2][2];   // [nf][ks], add 16384 + g*4096 at use
#pragma unroll
    for (int nf = 0; nf < 2; ++nf) {
        int n = wn * 32 + nf * 16 + l15;
#pragma unroll
        for (int ks = 0; ks < 2; ++ks) {
            int kc = ks * 4 + l4;
            boff[nf][ks] = n * 64 + (((kc ^ n) & 7) << 3);
        }
    }

    f32x4 acc[4][4][2] = {};   // [gate][mf][nf]
    short8 afr[4][2];          // A frags: read in phase 0, reused all 4 gates

// chunk staging: 2 gload_lds per thread per phase (= 2 vmcnt events per wave)
#define STAGE_A(c, kt, half)                                                   \
    { const u16* s_ = Abase + (size_t)(kt) * 16384 + (half) * 8192 +           \
                      (w * 2) * 512 + lane * 8;                                \
      u16* d_ = lds + (c) * 32768 + (half) * 8192 + (w * 2) * 512;             \
      gload16(s_, d_); gload16(s_ + 512, d_ + 512); }

#define STAGE_B(c, kt, pb)                                                     \
    { const u16* s0_ = Bbase + (size_t)((pb) * 2) * 16 * bstr +                \
                       (size_t)(kt) * 4096 + w * 512 + lane * 8;               \
      const u16* s1_ = Bbase + (size_t)((pb) * 2 + 1) * 16 * bstr +            \
                       (size_t)(kt) * 4096 + w * 512 + lane * 8;               \
      u16* d_ = lds + (c) * 32768 + 16384 + ((pb) * 2) * 4096 + w * 512;       \
      gload16(s0_, d_); gload16(s1_, d_ + 4096); }

#define PHASE(G, STAGE_STMT, TAIL_WAIT)                                        \
    { short8 bfr[2][2];                                                        \
      _Pragma("unroll") for (int nf = 0; nf < 2; ++nf)                         \
        _Pragma("unroll") for (int ks = 0; ks < 2; ++ks)                       \
          bfr[nf][ks] = *reinterpret_cast<const short8*>(                      \
              Bl + (G) * 4096 + boff[nf][ks]);                                 \
      STAGE_STMT;                                                              \
      __builtin_amdgcn_s_barrier();                                            \
      asm volatile("s_waitcnt lgkmcnt(0)");                                    \
      __builtin_amdgcn_s_setprio(1);                                           \
      _Pragma("unroll") for (int ks = 0; ks < 2; ++ks)                         \
        _Pragma("unroll") for (int mf = 0; mf < 4; ++mf)                       \
          _Pragma("unroll") for (int nf = 0; nf < 2; ++nf)                     \
            acc[G][mf][nf] = __builtin_amdgcn_mfma_f32_16x16x32_bf16(          \
                afr[mf][ks], bfr[nf][ks], acc[G][mf][nf], 0, 0, 0);            \
      __builtin_amdgcn_s_setprio(0);                                           \
      TAIL_WAIT;                                                               \
      __builtin_amdgcn_s_barrier(); }

    // ---- prologue: issue K-tile 0's 4 chunks (8 loads/wave), wait first 3 ----
    STAGE_A(0, 0, 0);
    STAGE_A(0, 0, 1);
    STAGE_B(0, 0, 0);
    STAGE_B(0, 0, 1);
    asm volatile("s_waitcnt vmcnt(2)");   // A0,A1,B01 landed; B23 in flight
    __builtin_amdgcn_s_barrier();

    for (int kt = 0; kt < NT; ++kt) {
        const int c = kt & 1;
        u16* Al = lds + c * 32768;
        u16* Bl = Al + 16384;
        const bool st = (kt < NT - 1);

        // phase 0: gate I — read A frags (reused by all gates) + B g0
#pragma unroll
        for (int mf = 0; mf < 4; ++mf)
#pragma unroll
            for (int ks = 0; ks < 2; ++ks)
                afr[mf][ks] = *reinterpret_cast<const short8*>(Al + aoff[mf][ks]);
        PHASE(0, if (st) STAGE_A(c ^ 1, kt + 1, 0), )

        // phase 1: gate F; drain this tile's B23 (all, on last tile)
        PHASE(1, if (st) STAGE_A(c ^ 1, kt + 1, 1),
              if (st) { asm volatile("s_waitcnt vmcnt(4)"); }
              else    { asm volatile("s_waitcnt vmcnt(0)"); })

        // phase 2: gate C
        PHASE(2, if (st) STAGE_B(c ^ 1, kt + 1, 0), )

        // phase 3: gate O; drain next tile's A0,A1,B01 (its B23 stays in flight)
        PHASE(3, if (st) STAGE_B(c ^ 1, kt + 1, 1),
              if (st) { asm volatile("s_waitcnt vmcnt(2)"); })
    }

    // ---- fused LSTM epilogue (all 4 gates wave-local) ----
    const int mBase = mblk * BM + wq * 64;
    const int nBase = nblk * BNS + wn * 32;
#pragma unroll
    for (int mf = 0; mf < 4; ++mf) {
#pragma unroll
        for (int nf = 0; nf < 2; ++nf) {
            int n = nBase + nf * 16 + l15;
            float vbi = b_i[n], vbf = b_f[n], vbc = b_c[n], vbo = b_o[n];
#pragma unroll
            for (int r = 0; r < 4; ++r) {
                int m = mBase + mf * 16 + l4 * 4 + r;
                size_t idx = (size_t)m * NDIM + n;
                float gi = sigm(acc[G_I][mf][nf][r] + vbi);
                float gf = sigm(acc[G_F][mf][nf][r] + vbf);
                float gc = tanhf(acc[G_C][mf][nf][r] + vbc);
                float go = sigm(acc[G_O][mf][nf][r] + vbo);
                float ct = gf * c_in[idx] + gi * gc;
                h_out[idx] = go * tanhf(ct);
                c_out[idx] = ct;
            }
        }
    }
#undef STAGE_A
#undef STAGE_B
#undef PHASE
}

extern "C" void kernel_launch(void* const* d_in, const int* in_sizes, int n_in,
                              void* d_out, int out_size, void* d_ws, size_t ws_size,
                              hipStream_t stream) {
    const float* x   = (const float*)d_in[0];
    const float* h   = (const float*)d_in[1];
    const float* c   = (const float*)d_in[2];
    const float* Wi  = (const float*)d_in[3];
    const float* Wf  = (const float*)d_in[4];
    const float* Wc  = (const float*)d_in[5];
    const float* Wo  = (const float*)d_in[6];
    const float* bi  = (const float*)d_in[7];
    const float* bf_ = (const float*)d_in[8];
    const float* bc  = (const float*)d_in[9];
    const float* bo  = (const float*)d_in[10];

    float* hout = (float*)d_out;
    float* cout = hout + (size_t)MDIM * NDIM;

    u16* xh_ws = (u16*)d_ws;                       // bf16 xh, 16.78 MB
    u16* w_ws  = xh_ws + (size_t)MDIM * KDIM;      // bf16 W^T, 16.78 MB

    conv_xh_kernel<<<dim3(32, 16), 256, 0, stream>>>(x, h, xh_ws);
    conv_w_kernel<<<dim3(32, 16, 4), 256, 0, stream>>>(Wi, Wf, Wc, Wo, w_ws);
    lstm_gemm_kernel<<<dim3(16, 16), 512, 0, stream>>>(
        xh_ws, w_ws, c, bi, bf_, bc, bo, hout, cout);
}